// Round 1
// baseline (1328.404 us; speedup 1.0000x reference)
//
#include <hip/hip_runtime.h>

// Spatially-varying 17x17 blur.
// img:     (B=4, C=3, 272, 272) fp32, pre-padded
// kernels: (16, 1, 289, 65536) fp32, per-pixel taps (normalized)
// idx:     scalar int (device)
// out:     (4, 3, 256, 256) fp32
//
// Design: one thread per output pixel p, accumulating ALL 12 (b,c) channels.
// - kern[k*P + p]: consecutive lanes -> consecutive addresses (perfectly
//   coalesced); each kern element loaded exactly once on the device -> HBM
//   traffic floor ~75.8 MB.
// - img loads coalesced along x; img is 3.5 MB total -> L1/L2 resident.
// - 12 fp32 accumulators per thread; inner kw x bc unrolled.

#define KS 17
#define HP 256
#define WP 256
#define IW (WP + KS - 1)          // 272
#define IH (HP + KS - 1)          // 272
#define NPIX (HP * WP)            // 65536
#define NBC 12                    // B*C = 4*3
#define CH_STRIDE (IW * IH)       // 73984

__global__ __launch_bounds__(256) void blur_pixel_kernel(
    const float* __restrict__ img,
    const float* __restrict__ kernels,
    const int* __restrict__ idx_p,
    float* __restrict__ out)
{
    const int p = blockIdx.x * 256 + threadIdx.x;   // pixel id, one row per block
    const int y = p >> 8;                           // WP == 256
    const int x = p & 255;

    // kernels[idx, 0, k, p]
    const float* kern = kernels + (long)idx_p[0] * (long)(KS * KS) * (long)NPIX + p;
    // img[0,0, y, x]
    const float* imgp = img + y * IW + x;

    float acc[NBC];
#pragma unroll
    for (int i = 0; i < NBC; ++i) acc[i] = 0.0f;

    for (int kh = 0; kh < KS; ++kh) {
#pragma unroll
        for (int kw = 0; kw < KS; ++kw) {
            const int k = kh * KS + kw;
            const float w = kern[(long)k * NPIX];
            const int off = kh * IW + kw;
#pragma unroll
            for (int bc = 0; bc < NBC; ++bc) {
                acc[bc] = fmaf(w, imgp[(long)bc * CH_STRIDE + off], acc[bc]);
            }
        }
    }

#pragma unroll
    for (int bc = 0; bc < NBC; ++bc) {
        out[bc * NPIX + p] = acc[bc];
    }
}

extern "C" void kernel_launch(void* const* d_in, const int* in_sizes, int n_in,
                              void* d_out, int out_size, void* d_ws, size_t ws_size,
                              hipStream_t stream) {
    const float* img     = (const float*)d_in[0];
    const float* kernels = (const float*)d_in[1];
    const int*   idx     = (const int*)d_in[2];
    float*       out     = (float*)d_out;

    blur_pixel_kernel<<<dim3(NPIX / 256), dim3(256), 0, stream>>>(img, kernels, idx, out);
}